// Round 1
// baseline (553.264 us; speedup 1.0000x reference)
//
#include <hip/hip_runtime.h>
#include <stdint.h>

#define D_MEM 2048
#define BATCH 4096
#define K_DIM 4096   // 2*D
#define N_DIM 8192   // 4*D

typedef __bf16 bf16x8 __attribute__((ext_vector_type(8)));
typedef float f32x4 __attribute__((ext_vector_type(4)));

typedef const void __attribute__((address_space(1)))* gas_t;
typedef void __attribute__((address_space(3)))* las_t;

__device__ __forceinline__ ushort f2b(float f) {
  union { float f; uint32_t u; } v; v.f = f;
  uint32_t u = v.u + 0x7fffu + ((v.u >> 16) & 1u);
  return (ushort)(u >> 16);
}
__device__ __forceinline__ float b2f(ushort s) {
  union { uint32_t u; float f; } v; v.u = ((uint32_t)s) << 16;
  return v.f;
}
__device__ __forceinline__ float sigm(float x) {
  return 1.0f / (1.0f + __expf(-x));
}

// ---------------------------------------------------------------------------
// Kernel 1: cast+concat  A[m][k] = bf16( k<D ? lh[m][k] : rh[m][k-D] )
// ---------------------------------------------------------------------------
__global__ void cast_concat_kernel(const float* __restrict__ lh,
                                   const float* __restrict__ rh,
                                   ushort* __restrict__ A) {
  int i4 = blockIdx.x * 256 + threadIdx.x;     // 4096*1024 float4 groups
  int row = i4 >> 10;
  int col = (i4 & 1023) * 4;
  const float* src = (col < D_MEM) ? (lh + (size_t)row * D_MEM + col)
                                   : (rh + (size_t)row * D_MEM + (col - D_MEM));
  float4 v = *(const float4*)src;
  ushort4 o; o.x = f2b(v.x); o.y = f2b(v.y); o.z = f2b(v.z); o.w = f2b(v.w);
  *(ushort4*)(A + (size_t)row * K_DIM + col) = o;
}

// ---------------------------------------------------------------------------
// Kernel 2: transpose+cast  Bt[n][k] = bf16( W[k - koff][n] ),  W = Wl or Wr
// 64x64 tiles via LDS (stride 65 -> conflict-free scalar reads/writes)
// ---------------------------------------------------------------------------
__global__ void transpose_cast_kernel(const float* __restrict__ Wl,
                                      const float* __restrict__ Wr,
                                      ushort* __restrict__ Bt) {
  __shared__ float t[64 * 65];
  const float* W = blockIdx.z ? Wr : Wl;
  int n0 = blockIdx.x * 64;
  int k0 = blockIdx.y * 64;
  int tid = threadIdx.x;
#pragma unroll
  for (int i = 0; i < 4; ++i) {
    int idx = i * 256 + tid;
    int rr = idx >> 4;            // k-local row 0..63
    int c4 = (idx & 15) * 4;      // n-local col
    float4 v = *(const float4*)(W + (size_t)(k0 + rr) * N_DIM + n0 + c4);
    t[rr * 65 + c4 + 0] = v.x;
    t[rr * 65 + c4 + 1] = v.y;
    t[rr * 65 + c4 + 2] = v.z;
    t[rr * 65 + c4 + 3] = v.w;
  }
  __syncthreads();
  int kbase = (blockIdx.z ? D_MEM : 0) + k0;
#pragma unroll
  for (int i = 0; i < 4; ++i) {
    int idx = i * 256 + tid;
    int rr = idx >> 4;            // n-local row 0..63
    int c4 = (idx & 15) * 4;      // k-local col
    ushort4 o;
    o.x = f2b(t[(c4 + 0) * 65 + rr]);
    o.y = f2b(t[(c4 + 1) * 65 + rr]);
    o.z = f2b(t[(c4 + 2) * 65 + rr]);
    o.w = f2b(t[(c4 + 3) * 65 + rr]);
    *(ushort4*)(Bt + (size_t)(n0 + rr) * K_DIM + kbase + c4) = o;
  }
}

// ---------------------------------------------------------------------------
// Kernel 3: GEMM  G[m][n] = sum_k A[m][k] * Bt[n][k]   (bf16 in, bf16 out)
// 128x128 tile, BK=64, 4 waves (2x2), 16x16x32 MFMA, global_load_lds staging.
// LDS layout: 16B chunks, chunk (row,c) stored at index row*8 + (c ^ (row&7))
//  -> staging is linear (wave-uniform base + lane*16) AND frag ds_read_b128
//     lands on all 8 bank groups (2-way = free).
// ---------------------------------------------------------------------------
__global__ __launch_bounds__(256) void gemm_bf16_kernel(
    const ushort* __restrict__ A,   // [M][K]
    const ushort* __restrict__ B,   // [N][K]
    ushort* __restrict__ C) {       // [M][N]
  const int N = N_DIM, K = K_DIM;
  __shared__ ushort As[128 * 64];
  __shared__ ushort Bs[128 * 64];
  int tid = threadIdx.x;
  int lane = tid & 63;
  int wave = tid >> 6;
  int wm = wave >> 1, wn = wave & 1;
  int q = lane >> 4, r = lane & 15;
  int m0 = blockIdx.y * 128, n0 = blockIdx.x * 128;

  // staging: slot s = t*256 + tid ; row = s/8 , c' = s%8 , c = c' ^ (row&7)
  int c_chunk = (tid & 7) ^ ((tid >> 3) & 7);
  int srow = tid >> 3;
  const ushort* pA = A + (size_t)(m0 + srow) * K + c_chunk * 8;
  const ushort* pB = B + (size_t)(n0 + srow) * K + c_chunk * 8;

  int aoff[4], boff[4];
#pragma unroll
  for (int f = 0; f < 4; ++f) {
    int ml = wm * 64 + f * 16 + r;
    aoff[f] = (ml * 8 + (q ^ (ml & 7))) * 16;
    int nl = wn * 64 + f * 16 + r;
    boff[f] = (nl * 8 + (q ^ (nl & 7))) * 16;
  }

  f32x4 acc[4][4];
#pragma unroll
  for (int i = 0; i < 4; ++i)
#pragma unroll
    for (int j = 0; j < 4; ++j) acc[i][j] = f32x4{0.f, 0.f, 0.f, 0.f};

  char* AsB = (char*)As;
  char* BsB = (char*)Bs;
  int ldsbase = wave * 1024;  // bytes; round t adds t*4096

  for (int kt = 0; kt < K / 64; ++kt) {
#pragma unroll
    for (int t2 = 0; t2 < 4; ++t2)
      __builtin_amdgcn_global_load_lds((gas_t)(pA + (size_t)t2 * 32 * K),
                                       (las_t)(AsB + t2 * 4096 + ldsbase),
                                       16, 0, 0);
#pragma unroll
    for (int t2 = 0; t2 < 4; ++t2)
      __builtin_amdgcn_global_load_lds((gas_t)(pB + (size_t)t2 * 32 * K),
                                       (las_t)(BsB + t2 * 4096 + ldsbase),
                                       16, 0, 0);
    __syncthreads();   // compiler drains vmcnt before s_barrier
#pragma unroll
    for (int ks = 0; ks < 2; ++ks) {
      bf16x8 af[4], bg[4];
#pragma unroll
      for (int f = 0; f < 4; ++f) {
        af[f] = *(const bf16x8*)(AsB + (aoff[f] ^ (ks * 64)));
        bg[f] = *(const bf16x8*)(BsB + (boff[f] ^ (ks * 64)));
      }
#pragma unroll
      for (int i = 0; i < 4; ++i)
#pragma unroll
        for (int j = 0; j < 4; ++j)
          acc[i][j] = __builtin_amdgcn_mfma_f32_16x16x32_bf16(
              af[i], bg[j], acc[i][j], 0, 0, 0);
    }
    __syncthreads();
    pA += 64;
    pB += 64;
  }

  // epilogue: C/D layout col=lane&15, row=(lane>>4)*4+reg
#pragma unroll
  for (int i = 0; i < 4; ++i) {
    int gm_base = m0 + wm * 64 + i * 16 + q * 4;
#pragma unroll
    for (int j = 0; j < 4; ++j) {
      int gn = n0 + wn * 64 + j * 16 + r;
      size_t base = (size_t)gm_base * N + gn;
#pragma unroll
      for (int e = 0; e < 4; ++e)
        C[base + (size_t)e * N] = f2b(acc[i][j][e]);
    }
  }
}

// ---------------------------------------------------------------------------
// Kernel 4: gating epilogue
// g = G + bl + br ; i,lf,rf = sigmoid ; u = tanh ; c = i*u + lf*lc + rf*rc
// h = tanh(c). out = [c ; h] fp32.
// ---------------------------------------------------------------------------
__global__ void gate_kernel(const ushort* __restrict__ G,
                            const float* __restrict__ bl,
                            const float* __restrict__ br,
                            const float* __restrict__ lc,
                            const float* __restrict__ rc,
                            float* __restrict__ out) {
  int i4 = blockIdx.x * 256 + threadIdx.x;   // 4096*512 groups
  int row = i4 >> 9;
  int col = (i4 & 511) * 4;
  size_t gbase = (size_t)row * N_DIM + col;

  ushort4 ui = *(const ushort4*)(G + gbase);
  ushort4 uf = *(const ushort4*)(G + gbase + 1 * D_MEM);
  ushort4 ug = *(const ushort4*)(G + gbase + 2 * D_MEM);
  ushort4 uu = *(const ushort4*)(G + gbase + 3 * D_MEM);

  float4 bli = *(const float4*)(bl + col);
  float4 blf = *(const float4*)(bl + col + 1 * D_MEM);
  float4 blr = *(const float4*)(bl + col + 2 * D_MEM);
  float4 blu = *(const float4*)(bl + col + 3 * D_MEM);
  float4 bri = *(const float4*)(br + col);
  float4 brf = *(const float4*)(br + col + 1 * D_MEM);
  float4 brr = *(const float4*)(br + col + 2 * D_MEM);
  float4 bru = *(const float4*)(br + col + 3 * D_MEM);

  float4 vlc = *(const float4*)(lc + (size_t)row * D_MEM + col);
  float4 vrc = *(const float4*)(rc + (size_t)row * D_MEM + col);

  float4 vc, vh;
  {
    float gi = b2f(ui.x) + bli.x + bri.x;
    float gf = b2f(uf.x) + blf.x + brf.x;
    float gr = b2f(ug.x) + blr.x + brr.x;
    float gu = b2f(uu.x) + blu.x + bru.x;
    vc.x = sigm(gi) * tanhf(gu) + sigm(gf) * vlc.x + sigm(gr) * vrc.x;
    vh.x = tanhf(vc.x);
  }
  {
    float gi = b2f(ui.y) + bli.y + bri.y;
    float gf = b2f(uf.y) + blf.y + brf.y;
    float gr = b2f(ug.y) + blr.y + brr.y;
    float gu = b2f(uu.y) + blu.y + bru.y;
    vc.y = sigm(gi) * tanhf(gu) + sigm(gf) * vlc.y + sigm(gr) * vrc.y;
    vh.y = tanhf(vc.y);
  }
  {
    float gi = b2f(ui.z) + bli.z + bri.z;
    float gf = b2f(uf.z) + blf.z + brf.z;
    float gr = b2f(ug.z) + blr.z + brr.z;
    float gu = b2f(uu.z) + blu.z + bru.z;
    vc.z = sigm(gi) * tanhf(gu) + sigm(gf) * vlc.z + sigm(gr) * vrc.z;
    vh.z = tanhf(vc.z);
  }
  {
    float gi = b2f(ui.w) + bli.w + bri.w;
    float gf = b2f(uf.w) + blf.w + brf.w;
    float gr = b2f(ug.w) + blr.w + brr.w;
    float gu = b2f(uu.w) + blu.w + bru.w;
    vc.w = sigm(gi) * tanhf(gu) + sigm(gf) * vlc.w + sigm(gr) * vrc.w;
    vh.w = tanhf(vc.w);
  }

  size_t obase = (size_t)row * D_MEM + col;
  *(float4*)(out + obase) = vc;
  *(float4*)(out + (size_t)BATCH * D_MEM + obase) = vh;
}

// ---------------------------------------------------------------------------
extern "C" void kernel_launch(void* const* d_in, const int* in_sizes, int n_in,
                              void* d_out, int out_size, void* d_ws, size_t ws_size,
                              hipStream_t stream) {
  const float* lc = (const float*)d_in[0];
  const float* lh = (const float*)d_in[1];
  const float* rc = (const float*)d_in[2];
  const float* rh = (const float*)d_in[3];
  const float* Wl = (const float*)d_in[4];
  const float* bl = (const float*)d_in[5];
  const float* Wr = (const float*)d_in[6];
  const float* br = (const float*)d_in[7];
  float* out = (float*)d_out;

  char* ws = (char*)d_ws;
  ushort* A  = (ushort*)ws;                                // 32 MB  bf16 [4096][4096]
  ushort* Bt = (ushort*)(ws + (size_t)32 * 1024 * 1024);   // 64 MB  bf16 [8192][4096]
  ushort* G  = (ushort*)(ws + (size_t)96 * 1024 * 1024);   // 64 MB  bf16 [4096][8192]

  cast_concat_kernel<<<16384, 256, 0, stream>>>(lh, rh, A);
  dim3 tg(128, 32, 2);
  transpose_cast_kernel<<<tg, 256, 0, stream>>>(Wl, Wr, Bt);
  dim3 gg(64, 32);
  gemm_bf16_kernel<<<gg, 256, 0, stream>>>(A, Bt, G);
  gate_kernel<<<8192, 256, 0, stream>>>(G, bl, br, lc, rc, out);
}